// Round 7
// baseline (492.613 us; speedup 1.0000x reference)
//
#include <hip/hip_runtime.h>

#define NB 8
#define NA 102400
#define NGRID 320
#define NG 16
#define NSUP 5
#define NQ 3
#define NCLSF 80.0f
#define NSLICE 16
#define SLS 264                          // slice stride: 256 sums + 4 counts + pad
#define WS_REG   (NSLICE * SLS)          // 4224: regSum[8]
#define WS_NPOS  (WS_REG + NB)           // 4232: nposSum[8]
#define WS_CLS   (WS_NPOS + NB)          // 4240: clsSum slices[4]
#define WS_NPQ   (WS_CLS + 4)            // 4244: npqSum slices[4]
#define WS_DONE  (WS_NPQ + 4)            // 4248: two uint done-counters
#define WS_P     4256                    // 256 normalized proto floats (16B aligned)
#define WS_Q     (WS_P + 256)            // 4512: |p_c|^2 [4]
#define WS_FLOATS (WS_Q + 4)             // 4516 floats
#define PROTO_BLOCKS (NSUP * 400)        // 2000
#define QUERY_BLOCKS (NQ * 400)          // 1200

__device__ __forceinline__ void anchor_of(int a, float& ax0, float& ay0,
                                          float& ax1, float& ay1) {
    int i = a / NGRID;
    int j = a - i * NGRID;
    ax0 = (float)j * 4.0f;
    ay0 = (float)i * 4.0f;
    ax1 = ax0 + 4.0f;
    ay1 = ay0 + 4.0f;
}

// iou over 16 boxes, FIRST-max argmax (strict >), target assignment.
__device__ __forceinline__ void assign_anchor(const float* ann, int a,
                                              float& tgt, int& arg, float& iou_max) {
    float ax0, ay0, ax1, ay1;
    anchor_of(a, ax0, ay0, ax1, ay1);
    float aw = ax1 - ax0, ah = ay1 - ay0;
    float aarea = aw * ah;
    float best = -1.0f;
    int bi = 0;
    #pragma unroll
    for (int j = 0; j < NG; ++j) {
        float bx0 = ann[j * 5 + 0], by0 = ann[j * 5 + 1];
        float bx1 = ann[j * 5 + 2], by1 = ann[j * 5 + 3];
        float iw = fmaxf(fminf(ax1, bx1) - fmaxf(ax0, bx0), 0.0f);
        float ih = fmaxf(fminf(ay1, by1) - fmaxf(ay0, by0), 0.0f);
        float inter = iw * ih;
        float area = (bx1 - bx0) * (by1 - by0);
        float ua = fmaxf(aarea + area - inter, 1e-8f);
        float iou = inter / ua;
        if (iou > best) { best = iou; bi = j; }
    }
    iou_max = best;
    arg = bi;
    float lab = ann[bi * 5 + 4];
    tgt = (best >= 0.5f) ? lab : ((best < 0.4f) ? NCLSF : -1.0f);
}

__device__ __forceinline__ int code_of(float tgt) {
    int vld = (tgt != -1.0f) ? 4 : 0;
    int tix = (tgt == NCLSF) ? 3 : ((tgt == 2.0f) ? 2 : ((tgt == 1.0f) ? 1 : 0));
    return tix | vld;
}

__device__ __forceinline__ void reg_partial(const float* ann, int a, int arg, float im,
                                            const float* __restrict__ regressions,
                                            size_t row, float& sl1, float& posf) {
    if (im >= 0.5f) {
        posf += 1.0f;
        float ax0, ay0, ax1, ay1;
        anchor_of(a, ax0, ay0, ax1, ay1);
        float aw = ax1 - ax0, ah = ay1 - ay0;
        float acx = ax0 + 0.5f * aw, acy = ay0 + 0.5f * ah;
        const float* bb = ann + arg * 5;
        float rgw = bb[2] - bb[0], rgh = bb[3] - bb[1];
        float gcx = bb[0] + 0.5f * rgw, gcy = bb[1] + 0.5f * rgh;
        float gw = fmaxf(rgw, 1.0f), gh = fmaxf(rgh, 1.0f);
        float t0 = ((gcx - acx) / aw) / 0.1f;
        float t1 = ((gcy - acy) / ah) / 0.1f;
        float t2 = logf(gw / aw) / 0.2f;
        float t3 = logf(gh / ah) / 0.2f;
        const float4 rg4 = *reinterpret_cast<const float4*>(regressions + row * 4);
        float d0 = fabsf(t0 - rg4.x), d1 = fabsf(t1 - rg4.y);
        float d2 = fabsf(t2 - rg4.z), d3 = fabsf(t3 - rg4.w);
        sl1 += (d0 <= (1.0f/9.0f)) ? (4.5f * d0 * d0) : (d0 - 0.5f/9.0f);
        sl1 += (d1 <= (1.0f/9.0f)) ? (4.5f * d1 * d1) : (d1 - 0.5f/9.0f);
        sl1 += (d2 <= (1.0f/9.0f)) ? (4.5f * d2 * d2) : (d2 - 0.5f/9.0f);
        sl1 += (d3 <= (1.0f/9.0f)) ? (4.5f * d3 * d3) : (d3 - 0.5f/9.0f);
    }
}

// ---------- support pass: proto sums/counts + reg partials; last block normalizes ----------
__global__ __launch_bounds__(256, 3) void fl_proto(const float* __restrict__ annotations,
                                                   const float* __restrict__ cls,
                                                   const float* __restrict__ regressions,
                                                   float* __restrict__ ws) {
    __shared__ float s_ann[NG * 5];
    __shared__ float s_acc[256];
    __shared__ float s_cnt[4];
    __shared__ float s_red[4][2];
    __shared__ int   s_last;
    const int tid = threadIdx.x, lane = tid & 63, wid = tid >> 6;
    const int rg = lane >> 4, li = lane & 15, zi = li * 4;
    const int b  = blockIdx.x / 400;
    const int cb = blockIdx.x - b * 400;
    const int chunk = cb * 4 + wid;
    const size_t row0 = (size_t)b * NA + (size_t)chunk * 64;

    // 16 streaming float4 loads in flight (rows row0+rg+4i, slot li) — MUST stay in regs
    const float4* P = (const float4*)cls + (row0 + rg) * 16 + li;
    float4 v0[8], v1[8];
    #pragma unroll
    for (int i = 0; i < 8; ++i) v0[i] = P[(size_t)i * 64];
    #pragma unroll
    for (int i = 0; i < 8; ++i) v1[i] = P[(size_t)(i + 8) * 64];

    if (tid < NG * 5) s_ann[tid] = annotations[b * NG * 5 + tid];
    s_acc[tid] = 0.0f;
    if (tid < 4) s_cnt[tid] = 0.0f;
    __syncthreads();

    // assignment + reg partial for own row (hides load latency)
    const int a = chunk * 64 + lane;
    float tgt; int arg; float im;
    assign_anchor(s_ann, a, tgt, arg, im);
    const int ci = code_of(tgt);
    float sl1 = 0.0f, posf = 0.0f;
    reg_partial(s_ann, a, arg, im, regressions, row0 + lane, sl1, posf);

    // predicated accumulate
    float acc[4][4] = {};
    #pragma unroll
    for (int i = 0; i < 8; ++i) {
        const int cq = __shfl(ci, 4 * i + rg, 64);
        #pragma unroll
        for (int c = 0; c < 4; ++c) {
            const float sel = (cq == (c | 4)) ? 1.0f : 0.0f;
            acc[c][0] = fmaf(sel, v0[i].x, acc[c][0]);
            acc[c][1] = fmaf(sel, v0[i].y, acc[c][1]);
            acc[c][2] = fmaf(sel, v0[i].z, acc[c][2]);
            acc[c][3] = fmaf(sel, v0[i].w, acc[c][3]);
        }
    }
    #pragma unroll
    for (int i = 0; i < 8; ++i) {
        const int cq = __shfl(ci, 4 * (i + 8) + rg, 64);
        #pragma unroll
        for (int c = 0; c < 4; ++c) {
            const float sel = (cq == (c | 4)) ? 1.0f : 0.0f;
            acc[c][0] = fmaf(sel, v1[i].x, acc[c][0]);
            acc[c][1] = fmaf(sel, v1[i].y, acc[c][1]);
            acc[c][2] = fmaf(sel, v1[i].z, acc[c][2]);
            acc[c][3] = fmaf(sel, v1[i].w, acc[c][3]);
        }
    }
    // per-class counts + reg reduce
    #pragma unroll
    for (int c = 0; c < 4; ++c) {
        unsigned long long m = __ballot(ci == (c | 4));
        if (lane == 0) atomicAdd(&s_cnt[c], (float)__popcll(m));
    }
    #pragma unroll
    for (int s = 1; s < 64; s <<= 1) {
        sl1  += __shfl_xor(sl1, s, 64);
        posf += __shfl_xor(posf, s, 64);
    }
    if (lane == 0) { s_red[wid][0] = sl1; s_red[wid][1] = posf; }
    // acc -> block LDS
    #pragma unroll
    for (int c = 0; c < 4; ++c) {
        #pragma unroll
        for (int k = 0; k < 4; ++k) {
            float vv = acc[c][k];
            vv += __shfl_xor(vv, 16, 64);
            vv += __shfl_xor(vv, 32, 64);
            if (lane < 16) atomicAdd(&s_acc[c * 64 + zi + k], vv);
        }
    }
    __syncthreads();
    const int slice = blockIdx.x & (NSLICE - 1);
    atomicAdd(&ws[slice * SLS + tid], s_acc[tid]);
    if (tid < 4 && s_cnt[tid] != 0.0f)
        atomicAdd(&ws[slice * SLS + 256 + tid], s_cnt[tid]);
    if (tid == 0) {
        atomicAdd(&ws[WS_REG + b],  s_red[0][0] + s_red[1][0] + s_red[2][0] + s_red[3][0]);
        atomicAdd(&ws[WS_NPOS + b], s_red[0][1] + s_red[1][1] + s_red[2][1] + s_red[3][1]);
    }
    // last block normalizes prototypes -> ws[WS_P..], |p|^2 -> ws[WS_Q..]
    __threadfence();
    if (tid == 0) {
        unsigned d = atomicAdd((unsigned*)(ws + WS_DONE), 1u);
        s_last = (d == PROTO_BLOCKS - 1u) ? 1 : 0;
    }
    __syncthreads();
    if (s_last) {
        __threadfence();
        float sum = 0.0f, cnt = 0.0f;
        #pragma unroll
        for (int s = 0; s < NSLICE; ++s) {
            sum += ws[s * SLS + tid];
            cnt += ws[s * SLS + 256 + (tid >> 6)];
        }
        const float p = sum / fmaxf(cnt, 1.0f);
        ws[WS_P + tid] = p;
        float sq = p * p;
        #pragma unroll
        for (int s = 1; s < 64; s <<= 1) sq += __shfl_xor(sq, s, 64);
        if (lane == 0) ws[WS_Q + wid] = sq;
    }
}

// ---------- query pass: per-lane-owns-row via swizzled LDS transpose; no cross-lane ops ----------
__global__ __launch_bounds__(256, 3) void fl_query(const float* __restrict__ annotations,
                                                   const float* __restrict__ cls,
                                                   const float* __restrict__ regressions,
                                                   const float* __restrict__ pf,   // ws+WS_P (256 p, then 4 |p|^2)
                                                   float* __restrict__ ws,
                                                   float* __restrict__ out) {
    __shared__ float4 s_st[4][512];      // 8 KB per wave, wave-private
    __shared__ float  s_ann[NG * 5];
    __shared__ float  s_red[4][4];
    __shared__ int    s_last;
    const int tid = threadIdx.x, lane = tid & 63, wid = tid >> 6;
    const int i8 = lane >> 3, k8 = lane & 7;
    const int qb = blockIdx.x / 400;
    const int b  = NSUP + qb;
    const int cb = blockIdx.x - qb * 400;
    const int chunk = cb * 4 + wid;
    const size_t row0 = (size_t)b * NA + (size_t)chunk * 64;

    // issue all 16 stage loads (2 stages x 8): load i covers rows i*8..i*8+7, 128B/row-segment
    float4 va[8], vb[8];
    #pragma unroll
    for (int i = 0; i < 8; ++i) {
        const int rr = i * 8 + i8;
        va[i] = ((const float4*)cls)[(row0 + rr) * 16 + k8];
    }
    #pragma unroll
    for (int i = 0; i < 8; ++i) {
        const int rr = i * 8 + i8;
        vb[i] = ((const float4*)cls)[(row0 + rr) * 16 + 8 + k8];
    }
    if (tid < NG * 5) s_ann[tid] = annotations[b * NG * 5 + tid];
    __syncthreads();

    // assignment + reg partial for own row (lane l owns row row0+l) — hides load latency
    const int a = chunk * 64 + lane;
    float tgt; int arg; float im;
    assign_anchor(s_ann, a, tgt, arg, im);
    const int code = code_of(tgt);
    float sl1 = 0.0f, posf = 0.0f;
    reg_partial(s_ann, a, arg, im, regressions, row0 + lane, sl1, posf);

    float4* st = s_st[wid];
    float acc0 = 0.0f, acc1 = 0.0f, acc2 = 0.0f, acc3 = 0.0f;

    // ---- stage A: slots 0..7 ----
    #pragma unroll
    for (int i = 0; i < 8; ++i) {
        const int rr = i * 8 + i8;
        st[rr * 8 + (k8 ^ (rr & 7))] = va[i];
    }
    #pragma unroll
    for (int k = 0; k < 8; ++k) {
        const float4 e = st[lane * 8 + (k ^ (lane & 7))];
        const float4 p0 = ((const float4*)pf)[0 * 16 + k];
        const float4 p1 = ((const float4*)pf)[1 * 16 + k];
        const float4 p2 = ((const float4*)pf)[2 * 16 + k];
        const float4 p3 = ((const float4*)pf)[3 * 16 + k];
        acc0 += e.x*p0.x + e.y*p0.y + e.z*p0.z + e.w*p0.w;
        acc1 += e.x*p1.x + e.y*p1.y + e.z*p1.z + e.w*p1.w;
        acc2 += e.x*p2.x + e.y*p2.y + e.z*p2.z + e.w*p2.w;
        acc3 += e.x*p3.x + e.y*p3.y + e.z*p3.z + e.w*p3.w;
    }
    // ---- stage B: slots 8..15 (reuses wave-private LDS; per-wave DS ordering) ----
    #pragma unroll
    for (int i = 0; i < 8; ++i) {
        const int rr = i * 8 + i8;
        st[rr * 8 + (k8 ^ (rr & 7))] = vb[i];
    }
    #pragma unroll
    for (int k = 0; k < 8; ++k) {
        const float4 e = st[lane * 8 + (k ^ (lane & 7))];
        const float4 p0 = ((const float4*)pf)[0 * 16 + 8 + k];
        const float4 p1 = ((const float4*)pf)[1 * 16 + 8 + k];
        const float4 p2 = ((const float4*)pf)[2 * 16 + 8 + k];
        const float4 p3 = ((const float4*)pf)[3 * 16 + 8 + k];
        acc0 += e.x*p0.x + e.y*p0.y + e.z*p0.z + e.w*p0.w;
        acc1 += e.x*p1.x + e.y*p1.y + e.z*p1.z + e.w*p1.w;
        acc2 += e.x*p2.x + e.y*p2.y + e.z*p2.z + e.w*p2.w;
        acc3 += e.x*p3.x + e.y*p3.y + e.z*p3.z + e.w*p3.w;
    }

    // per-lane softmax + focal (logits = 2*e.p - |p|^2; ||e||^2 cancels)
    const float l0 = 2.0f * acc0 - pf[256 + 0];
    const float l1 = 2.0f * acc1 - pf[256 + 1];
    const float l2 = 2.0f * acc2 - pf[256 + 2];
    const float l3 = 2.0f * acc3 - pf[256 + 3];
    const float m  = fmaxf(fmaxf(l0, l1), fmaxf(l2, l3));
    const float e0 = expf(l0 - m), e1 = expf(l1 - m);
    const float e2 = expf(l2 - m), e3 = expf(l3 - m);
    const float ssum = e0 + e1 + e2 + e3;
    const int tq = code & 3;
    const float pnum = (tq == 0) ? e0 : (tq == 1) ? e1 : (tq == 2) ? e2 : e3;
    const float prob = pnum / ssum;
    const float om = 1.0f - prob;
    float clsA = 0.0f, npqA = 0.0f;
    if (code & 4) {
        clsA = -0.25f * om * om * logf(prob);
        npqA = (tq != 3) ? 1.0f : 0.0f;
    }

    // wave + block reduce, sliced atomics
    #pragma unroll
    for (int s = 1; s < 64; s <<= 1) {
        clsA += __shfl_xor(clsA, s, 64);
        npqA += __shfl_xor(npqA, s, 64);
        sl1  += __shfl_xor(sl1, s, 64);
        posf += __shfl_xor(posf, s, 64);
    }
    if (lane == 0) {
        s_red[wid][0] = clsA; s_red[wid][1] = npqA;
        s_red[wid][2] = sl1;  s_red[wid][3] = posf;
    }
    __syncthreads();
    if (tid == 0) {
        const int slice = blockIdx.x & 3;
        atomicAdd(&ws[WS_CLS + slice], s_red[0][0] + s_red[1][0] + s_red[2][0] + s_red[3][0]);
        atomicAdd(&ws[WS_NPQ + slice], s_red[0][1] + s_red[1][1] + s_red[2][1] + s_red[3][1]);
        atomicAdd(&ws[WS_REG + b],  s_red[0][2] + s_red[1][2] + s_red[2][2] + s_red[3][2]);
        atomicAdd(&ws[WS_NPOS + b], s_red[0][3] + s_red[1][3] + s_red[2][3] + s_red[3][3]);
    }
    // last block finalizes the two outputs
    __threadfence();
    if (tid == 0) {
        unsigned d = atomicAdd((unsigned*)(ws + WS_DONE) + 1, 1u);
        s_last = (d == QUERY_BLOCKS - 1u) ? 1 : 0;
    }
    __syncthreads();
    if (s_last && tid == 0) {
        __threadfence();
        const float cs = ws[WS_CLS] + ws[WS_CLS+1] + ws[WS_CLS+2] + ws[WS_CLS+3];
        const float nq = ws[WS_NPQ] + ws[WS_NPQ+1] + ws[WS_NPQ+2] + ws[WS_NPQ+3];
        float rs = 0.0f;
        #pragma unroll
        for (int bb = 0; bb < NB; ++bb) {
            const float np_ = ws[WS_NPOS + bb];
            const float sv  = ws[WS_REG + bb];
            rs += (np_ > 0.0f) ? (sv / fmaxf(4.0f * np_, 1.0f)) : 0.0f;
        }
        out[0] = cs / fmaxf(nq, 1.0f);
        out[1] = rs * 0.125f;
    }
}

extern "C" void kernel_launch(void* const* d_in, const int* in_sizes, int n_in,
                              void* d_out, int out_size, void* d_ws, size_t ws_size,
                              hipStream_t stream) {
    const float* classifications = (const float*)d_in[0];
    const float* regressions    = (const float*)d_in[1];
    // d_in[2] (anchors) analytic: [4j, 4i, 4j+4, 4i+4] — recomputed on device.
    const float* annotations    = (const float*)d_in[3];
    float* ws  = (float*)d_ws;
    float* out = (float*)d_out;

    hipMemsetAsync(d_ws, 0, WS_FLOATS * sizeof(float), stream);
    fl_proto<<<PROTO_BLOCKS, 256, 0, stream>>>(annotations, classifications, regressions, ws);
    fl_query<<<QUERY_BLOCKS, 256, 0, stream>>>(annotations, classifications, regressions,
                                               ws + WS_P, ws, out);
}

// Round 8
// 127.266 us; speedup vs baseline: 3.8707x; 3.8707x over previous
//
#include <hip/hip_runtime.h>

#define NB 8
#define NA 102400
#define NGRID 320
#define NG 16
#define NSUP 5
#define NQ 3
#define NCLSF 80.0f
#define NSLICE 8
#define SLS 264                          // slice stride (256 sums + 4 counts + pad)
#define WS_REG   (NSLICE * SLS)          // 2112: regSum[8]
#define WS_NPOS  (WS_REG + NB)           // 2120: nposSum[8]
#define WS_CLS   (WS_NPOS + NB)          // 2128: clsSum slices[4]
#define WS_NPQ   (WS_CLS + 4)            // 2132: npqSum slices[4]
#define WS_FLOATS (WS_NPQ + 4)           // 2136 floats
#define BPI 400                          // blocks per image; 4 chunks(64 rows) per block

__device__ __forceinline__ void anchor_of(int a, float& ax0, float& ay0,
                                          float& ax1, float& ay1) {
    int i = a / NGRID;
    int j = a - i * NGRID;
    ax0 = (float)j * 4.0f;
    ay0 = (float)i * 4.0f;
    ax1 = ax0 + 4.0f;
    ay1 = ay0 + 4.0f;
}

// iou over 16 boxes, FIRST-max argmax (strict >), target assignment.
__device__ __forceinline__ void assign_anchor(const float* ann, int a,
                                              float& tgt, int& arg, float& iou_max) {
    float ax0, ay0, ax1, ay1;
    anchor_of(a, ax0, ay0, ax1, ay1);
    float aw = ax1 - ax0, ah = ay1 - ay0;
    float aarea = aw * ah;
    float best = -1.0f;
    int bi = 0;
    #pragma unroll
    for (int j = 0; j < NG; ++j) {
        float bx0 = ann[j * 5 + 0], by0 = ann[j * 5 + 1];
        float bx1 = ann[j * 5 + 2], by1 = ann[j * 5 + 3];
        float iw = fmaxf(fminf(ax1, bx1) - fmaxf(ax0, bx0), 0.0f);
        float ih = fmaxf(fminf(ay1, by1) - fmaxf(ay0, by0), 0.0f);
        float inter = iw * ih;
        float area = (bx1 - bx0) * (by1 - by0);
        float ua = fmaxf(aarea + area - inter, 1e-8f);
        float iou = inter / ua;
        if (iou > best) { best = iou; bi = j; }
    }
    iou_max = best;
    arg = bi;
    float lab = ann[bi * 5 + 4];
    tgt = (best >= 0.5f) ? lab : ((best < 0.4f) ? NCLSF : -1.0f);
}

__device__ __forceinline__ int code_of(float tgt) {
    int vld = (tgt != -1.0f) ? 4 : 0;
    int tix = (tgt == NCLSF) ? 3 : ((tgt == 2.0f) ? 2 : ((tgt == 1.0f) ? 1 : 0));
    return tix | vld;
}

// Per-lane reg-loss partial for this lane's own row (only if positive).
__device__ __forceinline__ void reg_partial(const float* ann, int a, int arg, float im,
                                            const float* __restrict__ regressions,
                                            size_t row, float& sl1, float& posf) {
    sl1 = 0.0f; posf = 0.0f;
    if (im >= 0.5f) {
        posf = 1.0f;
        float ax0, ay0, ax1, ay1;
        anchor_of(a, ax0, ay0, ax1, ay1);
        float aw = ax1 - ax0, ah = ay1 - ay0;
        float acx = ax0 + 0.5f * aw, acy = ay0 + 0.5f * ah;
        const float* bb = ann + arg * 5;
        float rgw = bb[2] - bb[0], rgh = bb[3] - bb[1];
        float gcx = bb[0] + 0.5f * rgw, gcy = bb[1] + 0.5f * rgh;
        float gw = fmaxf(rgw, 1.0f), gh = fmaxf(rgh, 1.0f);
        float t0 = ((gcx - acx) / aw) / 0.1f;
        float t1 = ((gcy - acy) / ah) / 0.1f;
        float t2 = logf(gw / aw) / 0.2f;
        float t3 = logf(gh / ah) / 0.2f;
        const float4 rg4 = *reinterpret_cast<const float4*>(regressions + row * 4);
        float d0 = fabsf(t0 - rg4.x), d1 = fabsf(t1 - rg4.y);
        float d2 = fabsf(t2 - rg4.z), d3 = fabsf(t3 - rg4.w);
        sl1 += (d0 <= (1.0f/9.0f)) ? (4.5f * d0 * d0) : (d0 - 0.5f/9.0f);
        sl1 += (d1 <= (1.0f/9.0f)) ? (4.5f * d1 * d1) : (d1 - 0.5f/9.0f);
        sl1 += (d2 <= (1.0f/9.0f)) ? (4.5f * d2 * d2) : (d2 - 0.5f/9.0f);
        sl1 += (d3 <= (1.0f/9.0f)) ? (4.5f * d3 * d3) : (d3 - 0.5f/9.0f);
    }
}

// Support images: inline assignment + prototype sums/counts + reg partials.
__global__ __launch_bounds__(256, 3) void fl_proto(const float* __restrict__ annotations,
                                                   const float* __restrict__ cls,
                                                   const float* __restrict__ regressions,
                                                   float* __restrict__ ws) {
    __shared__ float s_ann[NG * 5];
    __shared__ float s_acc[256];
    __shared__ float s_sl1[4], s_np[4];
    __shared__ int   s_cnt[4];
    int b    = blockIdx.x / BPI;
    int cb   = blockIdx.x - b * BPI;
    int wid  = threadIdx.x >> 6;
    int lane = threadIdx.x & 63;
    int rg   = lane >> 4, li = lane & 15, zi = li * 4;
    int chunk = cb * 4 + wid;                      // 0..1599 within image
    size_t row0 = (size_t)b * NA + (size_t)chunk * 64;

    // 1) issue the 16 streaming loads (16 KB/wave in flight), then PIN them:
    //    sched_barrier(0) forbids the scheduler from sinking these loads into
    //    the consume loop (which collapses VGPRs to 64 and kills MLP — r6/r7).
    float4 v[16];
    const float4* P = (const float4*)cls + (row0 + rg) * 16 + li;
    #pragma unroll
    for (int i = 0; i < 16; ++i) v[i] = P[(size_t)i * 64];
    __builtin_amdgcn_sched_barrier(0);

    // 2) stage annotations; zero block accumulators
    if (threadIdx.x < NG * 5) s_ann[threadIdx.x] = annotations[b * NG * 5 + threadIdx.x];
    s_acc[threadIdx.x] = 0.0f;
    if (threadIdx.x < 4) s_cnt[threadIdx.x] = 0;
    __syncthreads();

    // 3) per-lane assignment (hides load latency)
    int a = chunk * 64 + lane;
    float tgt; int arg; float im;
    assign_anchor(s_ann, a, tgt, arg, im);
    int ci = code_of(tgt);

    // 4) reg-loss partial for own row
    float sl1, posf;
    reg_partial(s_ann, a, arg, im, regressions, row0 + lane, sl1, posf);
    #pragma unroll
    for (int s = 1; s < 64; s <<= 1) {
        sl1  += __shfl_xor(sl1, s, 64);
        posf += __shfl_xor(posf, s, 64);
    }
    if (lane == 0) { s_sl1[wid] = sl1; s_np[wid] = posf; }

    // 5) prototype counts (support only)
    #pragma unroll
    for (int c = 0; c < 4; ++c) {
        unsigned long long m = __ballot(ci == (c | 4));
        if (lane == 0) atomicAdd(&s_cnt[c], (int)__popcll(m));
    }

    // 6) predicated accumulate of the 16 row-slices
    float acc[4][4] = {};
    #pragma unroll
    for (int i = 0; i < 16; ++i) {
        int cq = __shfl(ci, 4 * i + rg, 64);       // code of row row0+rg+4i
        #pragma unroll
        for (int c = 0; c < 4; ++c) {
            float sel = (cq == (c | 4)) ? 1.0f : 0.0f;
            acc[c][0] = fmaf(sel, v[i].x, acc[c][0]);
            acc[c][1] = fmaf(sel, v[i].y, acc[c][1]);
            acc[c][2] = fmaf(sel, v[i].z, acc[c][2]);
            acc[c][3] = fmaf(sel, v[i].w, acc[c][3]);
        }
    }
    // 7) rg-group reduce -> block LDS -> sliced global atomics
    #pragma unroll
    for (int c = 0; c < 4; ++c) {
        #pragma unroll
        for (int k = 0; k < 4; ++k) {
            float vv = acc[c][k];
            vv += __shfl_xor(vv, 16, 64);
            vv += __shfl_xor(vv, 32, 64);
            if (lane < 16) atomicAdd(&s_acc[c * 64 + zi + k], vv);
        }
    }
    __syncthreads();
    int slice = blockIdx.x & (NSLICE - 1);
    atomicAdd(&ws[slice * SLS + threadIdx.x], s_acc[threadIdx.x]);
    if (threadIdx.x < 4 && s_cnt[threadIdx.x] > 0)
        atomicAdd(&ws[slice * SLS + 256 + threadIdx.x], (float)s_cnt[threadIdx.x]);
    if (threadIdx.x == 0) {
        atomicAdd(&ws[WS_REG + b],  s_sl1[0] + s_sl1[1] + s_sl1[2] + s_sl1[3]);
        atomicAdd(&ws[WS_NPOS + b], s_np[0] + s_np[1] + s_np[2] + s_np[3]);
    }
}

// Query images: inline assignment + focal terms + reg partials.
__global__ __launch_bounds__(256, 3) void fl_query(const float* __restrict__ annotations,
                                                   const float* __restrict__ cls,
                                                   const float* __restrict__ regressions,
                                                   float* __restrict__ ws) {
    __shared__ float s_ann[NG * 5];
    __shared__ float s_cls[4], s_npq[4], s_sl1[4], s_np[4];
    int qb   = blockIdx.x / BPI;
    int b    = NSUP + qb;
    int cb   = blockIdx.x - qb * BPI;
    int wid  = threadIdx.x >> 6;
    int lane = threadIdx.x & 63;
    int rg   = lane >> 4, li = lane & 15, zi = li * 4;
    int chunk = cb * 4 + wid;
    size_t row0 = (size_t)b * NA + (size_t)chunk * 64;

    // 1) issue the 16 streaming loads, pinned (see fl_proto comment)
    float4 v[16];
    const float4* P = (const float4*)cls + (row0 + rg) * 16 + li;
    #pragma unroll
    for (int i = 0; i < 16; ++i) v[i] = P[(size_t)i * 64];
    __builtin_amdgcn_sched_barrier(0);

    if (threadIdx.x < NG * 5) s_ann[threadIdx.x] = annotations[b * NG * 5 + threadIdx.x];
    __syncthreads();

    // 2) build per-lane proto slice + |p|^2 (reads 8.4 KB ws, L2-hot)
    float p[4][4], q[4];
    #pragma unroll
    for (int c = 0; c < 4; ++c) {
        float cv = 0.0f, s0 = 0.0f, s1 = 0.0f, s2 = 0.0f, s3 = 0.0f;
        #pragma unroll
        for (int s = 0; s < NSLICE; ++s) {
            cv += ws[s * SLS + 256 + c];
            const float4 u = *reinterpret_cast<const float4*>(&ws[s * SLS + c * 64 + zi]);
            s0 += u.x; s1 += u.y; s2 += u.z; s3 += u.w;
        }
        cv = fmaxf(cv, 1.0f);
        p[c][0] = s0 / cv; p[c][1] = s1 / cv; p[c][2] = s2 / cv; p[c][3] = s3 / cv;
        float qp = p[c][0]*p[c][0] + p[c][1]*p[c][1] + p[c][2]*p[c][2] + p[c][3]*p[c][3];
        qp += __shfl_xor(qp, 1, 64);
        qp += __shfl_xor(qp, 2, 64);
        qp += __shfl_xor(qp, 4, 64);
        qp += __shfl_xor(qp, 8, 64);
        q[c] = qp;
    }

    // 3) per-lane assignment + reg partial
    int a = chunk * 64 + lane;
    float tgt; int arg; float im;
    assign_anchor(s_ann, a, tgt, arg, im);
    int code = code_of(tgt);
    float sl1, posf;
    reg_partial(s_ann, a, arg, im, regressions, row0 + lane, sl1, posf);

    // 4) focal terms over the 16 row-slices
    float clsAcc = 0.0f, npqAcc = 0.0f;
    #pragma unroll
    for (int i = 0; i < 16; ++i) {
        int cq = __shfl(code, 4 * i + rg, 64);
        float d0 = v[i].x*p[0][0] + v[i].y*p[0][1] + v[i].z*p[0][2] + v[i].w*p[0][3];
        float d1 = v[i].x*p[1][0] + v[i].y*p[1][1] + v[i].z*p[1][2] + v[i].w*p[1][3];
        float d2 = v[i].x*p[2][0] + v[i].y*p[2][1] + v[i].z*p[2][2] + v[i].w*p[2][3];
        float d3 = v[i].x*p[3][0] + v[i].y*p[3][1] + v[i].z*p[3][2] + v[i].w*p[3][3];
        #pragma unroll
        for (int s = 1; s < 16; s <<= 1) {
            d0 += __shfl_xor(d0, s, 64);
            d1 += __shfl_xor(d1, s, 64);
            d2 += __shfl_xor(d2, s, 64);
            d3 += __shfl_xor(d3, s, 64);
        }
        float l0 = 2.0f * d0 - q[0];
        float l1 = 2.0f * d1 - q[1];
        float l2 = 2.0f * d2 - q[2];
        float l3 = 2.0f * d3 - q[3];
        float m = fmaxf(fmaxf(l0, l1), fmaxf(l2, l3));
        float ex0 = expf(l0 - m), ex1 = expf(l1 - m);
        float ex2 = expf(l2 - m), ex3 = expf(l3 - m);
        float ssum = ex0 + ex1 + ex2 + ex3;
        int tq = cq & 3;
        float pnum = (tq == 0) ? ex0 : (tq == 1) ? ex1 : (tq == 2) ? ex2 : ex3;
        float prob = pnum / ssum;
        float om = 1.0f - prob;
        float term = -0.25f * om * om * logf(prob);
        if (li == 0 && (cq & 4)) {
            clsAcc += term;
            if (tq != 3) npqAcc += 1.0f;
        }
    }

    // 5) wave + block reduction, sliced atomics
    #pragma unroll
    for (int s = 1; s < 64; s <<= 1) {
        clsAcc += __shfl_xor(clsAcc, s, 64);
        npqAcc += __shfl_xor(npqAcc, s, 64);
        sl1    += __shfl_xor(sl1, s, 64);
        posf   += __shfl_xor(posf, s, 64);
    }
    if (lane == 0) { s_cls[wid] = clsAcc; s_npq[wid] = npqAcc; s_sl1[wid] = sl1; s_np[wid] = posf; }
    __syncthreads();
    if (threadIdx.x == 0) {
        int slice = blockIdx.x & 3;
        atomicAdd(&ws[WS_CLS + slice], s_cls[0] + s_cls[1] + s_cls[2] + s_cls[3]);
        atomicAdd(&ws[WS_NPQ + slice], s_npq[0] + s_npq[1] + s_npq[2] + s_npq[3]);
        atomicAdd(&ws[WS_REG + b],  s_sl1[0] + s_sl1[1] + s_sl1[2] + s_sl1[3]);
        atomicAdd(&ws[WS_NPOS + b], s_np[0] + s_np[1] + s_np[2] + s_np[3]);
    }
}

__global__ void fl_final(const float* __restrict__ ws, float* __restrict__ out) {
    if (threadIdx.x == 0 && blockIdx.x == 0) {
        float cs = ws[WS_CLS] + ws[WS_CLS+1] + ws[WS_CLS+2] + ws[WS_CLS+3];
        float nq = ws[WS_NPQ] + ws[WS_NPQ+1] + ws[WS_NPQ+2] + ws[WS_NPQ+3];
        float clsl = cs / fmaxf(nq, 1.0f);
        float rs = 0.0f;
        #pragma unroll
        for (int b = 0; b < NB; ++b) {
            float np_ = ws[WS_NPOS + b];
            float sv  = ws[WS_REG + b];
            rs += (np_ > 0.0f) ? (sv / fmaxf(4.0f * np_, 1.0f)) : 0.0f;
        }
        out[0] = clsl;
        out[1] = rs * 0.125f;
    }
}

extern "C" void kernel_launch(void* const* d_in, const int* in_sizes, int n_in,
                              void* d_out, int out_size, void* d_ws, size_t ws_size,
                              hipStream_t stream) {
    const float* classifications = (const float*)d_in[0];
    const float* regressions    = (const float*)d_in[1];
    // d_in[2] (anchors) analytic: [4j, 4i, 4j+4, 4i+4] — recomputed on device.
    const float* annotations    = (const float*)d_in[3];
    float* ws  = (float*)d_ws;
    float* out = (float*)d_out;

    hipMemsetAsync(d_ws, 0, WS_FLOATS * sizeof(float), stream);
    fl_proto<<<NSUP * BPI, 256, 0, stream>>>(annotations, classifications, regressions, ws);
    fl_query<<<NQ * BPI, 256, 0, stream>>>(annotations, classifications, regressions, ws);
    fl_final<<<1, 64, 0, stream>>>(ws, out);
}